// Round 3
// baseline (462.737 us; speedup 1.0000x reference)
//
#include <hip/hip_runtime.h>

// Problem constants (from reference setup_inputs)
#define NN 8
#define CC 4
#define HH 64
#define WW 64
#define KK 5
#define FF 16
#define HO 60
#define WO 60
#define PP (KK * KK * CC) /* 100 */

#define RPB 2                    /* output rows per block (and per wave) */
#define HPB (HO / RPB)           /* 30 ho-pairs per n */
#define NB (NN * HPB)            /* 240 blocks */
#define RIN (RPB + KK - 1)       /* 6 input rows per channel */

typedef float v4f __attribute__((ext_vector_type(4)));
typedef float v2f __attribute__((ext_vector_type(2)));

#define PQ_ELEMS (CC * RIN * 64) /* 1536 */
#define PQ_SIZE (PQ_ELEMS + 4)   /* +4 pad: last row lanes read lane+kw<=67 */
#define WL_ELEMS (PP * 16)       /* 1600 */
#define LDS_TOT (PQ_SIZE + WL_ELEMS) /* 3140 v4f = 50.24 KB */

// Round-3 theory: round-1 (31us conv) was LDS-read bound: 250 b128/wave for
// ONE output row, 80% of them wave-uniform weight re-reads. Round-2 proved
// global/vmcnt weights are worse (44us). Fix: 2 output rows per wave (weights
// read once per wave serve both rows; pixel rows register-shift across kh):
// 130 b128/wave for TWO rows. 240 blocks x 16 waves (4 fg x 4 c) = 4
// waves/SIMD. 4-way c-reduction through an LDS buffer overlaid on pq/wlds
// (dead after the inner loop) keeps LDS at 50.2 KB. Single fused kernel.
__global__ __launch_bounds__(1024) void smorph_fused(
        const float* __restrict__ x, const float* __restrict__ k1,
        const float* __restrict__ k2, const float* __restrict__ bias,
        float* __restrict__ out) {
    __shared__ v4f lds[LDS_TOT];
    v4f* pq = lds;            // [c][rin][64] pixel quads {e^x, x e^x, e^-x, -x e^-x}
    v4f* wl = lds + PQ_SIZE;  // [p][side][f2] weight quads {e^ka, e^kb, ka e^ka, kb e^kb}

    int b = blockIdx.x;       // 0..239 = (n, ho-pair)
    int n = b / HPB;
    int ho0 = (b - n * HPB) * RPB;
    int t = threadIdx.x;

    // Stage weight exp-quads (1600 elems, ~2 per thread; k1/k2 L2-resident).
    for (int i = t; i < WL_ELEMS; i += 1024) {
        int p = i >> 4, rem = i & 15, side = rem >> 3, f2 = rem & 7;
        const float* kp = side ? k2 : k1;
        float ka = kp[p * FF + 2 * f2];
        float kb = kp[p * FF + 2 * f2 + 1];
        float ea = __expf(ka), eb = __expf(kb);
        wl[i] = (v4f){ea, eb, ka * ea, kb * eb};
    }
    // Stage pixel exp-quads: input rows ho0..ho0+5 (ho0<=58 -> row<=63), all c.
    for (int i = t; i < PQ_ELEMS; i += 1024) {
        int w = i & 63;
        int cr = i >> 6; // c*RIN + r
        int c = cr / RIN, r = cr - c * RIN;
        float v = x[((n * CC + c) * HH + (ho0 + r)) * WW + w];
        float e1 = __expf(v), e2 = __expf(-v);
        pq[i] = (v4f){e1, v * e1, e2, -v * e2};
    }
    __syncthreads();

    int lane = t & 63; // w position (60 used)
    int wid = t >> 6;  // 0..15
    int fg = wid & 3;  // feature group: features 4fg..4fg+3
    int cw = wid >> 2; // channel owned by this wave

    v2f d1[RPB][2], n1[RPB][2], d2[RPB][2], n2[RPB][2];
#pragma unroll
    for (int r = 0; r < RPB; ++r)
#pragma unroll
        for (int jp = 0; jp < 2; ++jp) {
            d1[r][jp] = 0.f; n1[r][jp] = 0.f;
            d2[r][jp] = 0.f; n2[r][jp] = 0.f;
        }

    const v4f* pbase = pq + (cw * RIN) * 64 + lane;
    v4f q0[KK], q1[KK]; // pixel quads for rows kh, kh+1 (kw-shifted windows)
#pragma unroll
    for (int kw = 0; kw < KK; ++kw) {
        q0[kw] = pbase[kw];
        q1[kw] = pbase[64 + kw];
    }
#pragma unroll
    for (int kh = 0; kh < KK; ++kh) {
        if (kh) { // shift: row kh comes from regs, load row kh+1
#pragma unroll
            for (int kw = 0; kw < KK; ++kw) {
                q0[kw] = q1[kw];
                q1[kw] = pbase[(kh + 1) * 64 + kw];
            }
        }
#pragma unroll
        for (int kw = 0; kw < KK; ++kw) {
            // p = (kh*KK + kw)*CC + cw (reference patch order: kh,kw,c)
            const v4f* wp = wl + ((kh * KK + kw) * CC + cw) * 16 + fg * 2;
            v4f w1a = wp[0], w1b = wp[1]; // side 1 (k1), f-pairs 2fg, 2fg+1
            v4f w2a = wp[8], w2b = wp[9]; // side 2 (k2)
            v4f qq[RPB] = {q0[kw], q1[kw]};
#pragma unroll
            for (int r = 0; r < RPB; ++r) {
                v4f q = qq[r];
                d1[r][0] += q.xx * w1a.xy;
                n1[r][0] += q.yy * w1a.xy + q.xx * w1a.zw;
                d1[r][1] += q.xx * w1b.xy;
                n1[r][1] += q.yy * w1b.xy + q.xx * w1b.zw;
                d2[r][0] += q.zz * w2a.xy;
                n2[r][0] += q.ww * w2a.xy + q.zz * w2a.zw;
                d2[r][1] += q.zz * w2b.xy;
                n2[r][1] += q.ww * w2b.xy + q.zz * w2b.zw;
            }
        }
    }

    // 4-way c reduction per row through LDS overlay (pq/wlds dead now).
    // red[cw-1][fg][acc 0..3][lane], acc packs {v[0].xy, v[1].xy}: 3072 v4f.
    v4f* red = lds;
    __syncthreads();
#pragma unroll
    for (int r = 0; r < RPB; ++r) {
        if (r) __syncthreads(); // row-0 reads done before row-1 overwrites
        if (cw) {
            v4f* rr = red + (((cw - 1) * 4 + fg) * 4) * 64 + lane;
            rr[0 * 64] = (v4f){d1[r][0].x, d1[r][0].y, d1[r][1].x, d1[r][1].y};
            rr[1 * 64] = (v4f){n1[r][0].x, n1[r][0].y, n1[r][1].x, n1[r][1].y};
            rr[2 * 64] = (v4f){d2[r][0].x, d2[r][0].y, d2[r][1].x, d2[r][1].y};
            rr[3 * 64] = (v4f){n2[r][0].x, n2[r][0].y, n2[r][1].x, n2[r][1].y};
        }
        __syncthreads();
        if (!cw) {
#pragma unroll
            for (int rcw = 0; rcw < 3; ++rcw) {
                const v4f* rr = red + ((rcw * 4 + fg) * 4) * 64 + lane;
                v4f t0 = rr[0 * 64], t1 = rr[1 * 64];
                v4f t2 = rr[2 * 64], t3 = rr[3 * 64];
                d1[r][0] += t0.xy; d1[r][1] += t0.zw;
                n1[r][0] += t1.xy; n1[r][1] += t1.zw;
                d2[r][0] += t2.xy; d2[r][1] += t2.zw;
                n2[r][0] += t3.xy; n2[r][1] += t3.zw;
            }
            if (lane < WO) {
                int ho = ho0 + r;
#pragma unroll
                for (int jp = 0; jp < 2; ++jp) {
                    v2f o = n1[r][jp] / d1[r][jp] + n2[r][jp] / d2[r][jp];
                    int f0 = fg * 4 + 2 * jp;
                    out[((size_t)(n * FF + f0) * HO + ho) * WO + lane] =
                        o.x + bias[f0];
                    out[((size_t)(n * FF + f0 + 1) * HO + ho) * WO + lane] =
                        o.y + bias[f0 + 1];
                }
            }
        }
    }
}

extern "C" void kernel_launch(void* const* d_in, const int* in_sizes, int n_in,
                              void* d_out, int out_size, void* d_ws, size_t ws_size,
                              hipStream_t stream) {
    const float* x    = (const float*)d_in[0];
    const float* k1   = (const float*)d_in[1];
    const float* k2   = (const float*)d_in[2];
    const float* bias = (const float*)d_in[3];
    float* out = (float*)d_out;

    // 240 blocks (n, ho-pair), 1024 threads = 16 waves (4 fg x 4 c),
    // each wave computes 2 output rows for its 4 features / 1 channel.
    smorph_fused<<<NB, 1024, 0, stream>>>(x, k1, k2, bias, out);
}

// Round 4
// 289.757 us; speedup vs baseline: 1.5970x; 1.5970x over previous
//
#include <hip/hip_runtime.h>

// Problem constants (from reference setup_inputs)
#define NN 8
#define CC 4
#define HH 64
#define WW 64
#define KK 5
#define FF 16
#define HO 60
#define WO 60
#define PP (KK * KK * CC) /* 100 */

#define RPB 2                    /* output rows per block (and per wave) */
#define HPB (HO / RPB)           /* 30 ho-pairs per n */
#define RIN (RPB + KK - 1)       /* 6 input rows per channel */

typedef float v4f __attribute__((ext_vector_type(4)));
typedef float v2f __attribute__((ext_vector_type(2)));

#define PQ_ELEMS (CC * RIN * 64)     /* 1536 */
#define PQ_SIZE (PQ_ELEMS + 4)       /* +4 pad: last-row lanes read lane+kw<=67 */
#define WL_ELEMS (PP * 8)            /* 800: only this block's 8 features */
#define LDS_TOT (PQ_SIZE + WL_ELEMS) /* 2340 v4f = 37.4 KB */

// Round-4: round-3's 414us was pure VGPR spill (launch_bounds(1024) -> 64
// VGPR cap vs ~110 live; FETCH+WRITE = 1.27 GB scratch). Same amortization
// idea, fitted to registers: 512-thread blocks (8 waves), grid 480 =
// (n, ho-pair, f-half). Each wave: 1 channel, 2 local f-pairs (4 features),
// 2 output rows. LDS reads/wave: 100 weight quads (serve BOTH rows) + 30
// pixel quads (register row-shift across kh) = 130 b128 -- vs 250/row in the
// round-1 structure. 4-way c-reduction via LDS overlay on pq (dead then).
__global__ __launch_bounds__(512) void smorph_fused(
        const float* __restrict__ x, const float* __restrict__ k1,
        const float* __restrict__ k2, const float* __restrict__ bias,
        float* __restrict__ out) {
    __shared__ v4f lds[LDS_TOT];
    v4f* pq = lds;            // [c][rin][64] pixel quads {e^x, x e^x, e^-x, -x e^-x}
    v4f* wl = lds + PQ_SIZE;  // [p][side][f2l] weight quads {e^ka, e^kb, ka e^ka, kb e^kb}

    int b = blockIdx.x;       // 0..479 = (n, ho-pair, f-half)
    int n = b / (HPB * 2);
    int rem = b - n * (HPB * 2);
    int hp = rem >> 1;
    int fgh = rem & 1;        // feature half: features 8*fgh .. 8*fgh+7
    int ho0 = hp * RPB;
    int t = threadIdx.x;

    // Stage this f-half's weight exp-quads (800 elems; k1/k2 L2-resident).
    for (int i = t; i < WL_ELEMS; i += 512) {
        int p = i >> 3, r2 = i & 7, side = r2 >> 2, f2l = r2 & 3;
        int f2 = fgh * 4 + f2l; // global feature pair
        const float* kp = side ? k2 : k1;
        float ka = kp[p * FF + 2 * f2];
        float kb = kp[p * FF + 2 * f2 + 1];
        float ea = __expf(ka), eb = __expf(kb);
        wl[i] = (v4f){ea, eb, ka * ea, kb * eb};
    }
    // Stage pixel exp-quads: input rows ho0..ho0+5 (ho0<=58 -> row<=63), all c.
    for (int i = t; i < PQ_ELEMS; i += 512) {
        int w = i & 63;
        int cr = i >> 6; // c*RIN + r
        int c = cr / RIN, r = cr - c * RIN;
        float v = x[((n * CC + c) * HH + (ho0 + r)) * WW + w];
        float e1 = __expf(v), e2 = __expf(-v);
        pq[i] = (v4f){e1, v * e1, e2, -v * e2};
    }
    __syncthreads();

    int lane = t & 63; // w position (60 used)
    int wid = t >> 6;  // 0..7
    int cw = wid & 3;  // channel owned by this wave
    int fgl = wid >> 2;// local feature group: local f-pairs 2fgl, 2fgl+1

    v2f d1[RPB][2], n1[RPB][2], d2[RPB][2], n2[RPB][2];
#pragma unroll
    for (int r = 0; r < RPB; ++r)
#pragma unroll
        for (int jp = 0; jp < 2; ++jp) {
            d1[r][jp] = 0.f; n1[r][jp] = 0.f;
            d2[r][jp] = 0.f; n2[r][jp] = 0.f;
        }

    const v4f* pbase = pq + (cw * RIN) * 64 + lane;
    v4f q0[KK], q1[KK]; // pixel quads for rows kh, kh+1 (kw-shifted windows)
#pragma unroll
    for (int kw = 0; kw < KK; ++kw) {
        q0[kw] = pbase[kw];
        q1[kw] = pbase[64 + kw];
    }
#pragma unroll
    for (int kh = 0; kh < KK; ++kh) {
        if (kh) { // shift: row kh from regs, load row kh+1
#pragma unroll
            for (int kw = 0; kw < KK; ++kw) {
                q0[kw] = q1[kw];
                q1[kw] = pbase[(kh + 1) * 64 + kw];
            }
        }
#pragma unroll
        for (int kw = 0; kw < KK; ++kw) {
            // p = (kh*KK + kw)*CC + cw (reference patch order: kh,kw,c)
            const v4f* wp = wl + ((kh * KK + kw) * CC + cw) * 8 + fgl * 2;
            v4f w1a = wp[0], w1b = wp[1]; // side 1 (k1), local f-pairs
            v4f w2a = wp[4], w2b = wp[5]; // side 2 (k2)
            v4f qq[RPB] = {q0[kw], q1[kw]};
#pragma unroll
            for (int r = 0; r < RPB; ++r) {
                v4f q = qq[r];
                d1[r][0] += q.xx * w1a.xy;
                n1[r][0] += q.yy * w1a.xy + q.xx * w1a.zw;
                d1[r][1] += q.xx * w1b.xy;
                n1[r][1] += q.yy * w1b.xy + q.xx * w1b.zw;
                d2[r][0] += q.zz * w2a.xy;
                n2[r][0] += q.ww * w2a.xy + q.zz * w2a.zw;
                d2[r][1] += q.zz * w2b.xy;
                n2[r][1] += q.ww * w2b.xy + q.zz * w2b.zw;
            }
        }
    }

    // 4-way c-reduction per row via LDS overlay (pq dead; 1536 v4f needed).
    // red[(cw-1)][fgl][acc 0..3][lane], acc packs {v[0].xy, v[1].xy}.
    v4f* red = lds;
    __syncthreads();
#pragma unroll
    for (int r = 0; r < RPB; ++r) {
        if (r) __syncthreads(); // row-0 reads done before row-1 overwrites
        if (cw) {
            v4f* rr = red + (((cw - 1) * 2 + fgl) * 4) * 64 + lane;
            rr[0 * 64] = (v4f){d1[r][0].x, d1[r][0].y, d1[r][1].x, d1[r][1].y};
            rr[1 * 64] = (v4f){n1[r][0].x, n1[r][0].y, n1[r][1].x, n1[r][1].y};
            rr[2 * 64] = (v4f){d2[r][0].x, d2[r][0].y, d2[r][1].x, d2[r][1].y};
            rr[3 * 64] = (v4f){n2[r][0].x, n2[r][0].y, n2[r][1].x, n2[r][1].y};
        }
        __syncthreads();
        if (!cw) {
#pragma unroll
            for (int rcw = 0; rcw < 3; ++rcw) {
                const v4f* rr = red + ((rcw * 2 + fgl) * 4) * 64 + lane;
                v4f t0 = rr[0 * 64], t1 = rr[1 * 64];
                v4f t2 = rr[2 * 64], t3 = rr[3 * 64];
                d1[r][0] += t0.xy; d1[r][1] += t0.zw;
                n1[r][0] += t1.xy; n1[r][1] += t1.zw;
                d2[r][0] += t2.xy; d2[r][1] += t2.zw;
                n2[r][0] += t3.xy; n2[r][1] += t3.zw;
            }
            if (lane < WO) {
                int ho = ho0 + r;
#pragma unroll
                for (int jp = 0; jp < 2; ++jp) {
                    v2f o = n1[r][jp] / d1[r][jp] + n2[r][jp] / d2[r][jp];
                    int f0 = fgh * 8 + fgl * 4 + 2 * jp;
                    out[((size_t)(n * FF + f0) * HO + ho) * WO + lane] =
                        o.x + bias[f0];
                    out[((size_t)(n * FF + f0 + 1) * HO + ho) * WO + lane] =
                        o.y + bias[f0 + 1];
                }
            }
        }
    }
}

extern "C" void kernel_launch(void* const* d_in, const int* in_sizes, int n_in,
                              void* d_out, int out_size, void* d_ws, size_t ws_size,
                              hipStream_t stream) {
    const float* x    = (const float*)d_in[0];
    const float* k1   = (const float*)d_in[1];
    const float* k2   = (const float*)d_in[2];
    const float* bias = (const float*)d_in[3];
    float* out = (float*)d_out;

    // 480 blocks = 8 n x 30 ho-pairs x 2 f-halves; 512 threads = 8 waves
    // (4 channels x 2 local f-groups), each wave: 2 rows x 4 features x 1 c.
    smorph_fused<<<NN * HPB * 2, 512, 0, stream>>>(x, k1, k2, bias, out);
}

// Round 7
// 71.455 us; speedup vs baseline: 6.4760x; 4.0551x over previous
//
#include <hip/hip_runtime.h>

// Problem constants (from reference setup_inputs)
#define NN 8
#define CC 4
#define HH 64
#define WW 64
#define KK 5
#define FF 16
#define HO 60
#define WO 60
#define PP (KK * KK * CC) /* 100 */

#define RPB 2                    /* output rows per block (and per wave) */
#define HPB (HO / RPB)           /* 30 ho-pairs per n */
#define RIN (RPB + KK - 1)       /* 6 input rows per channel */

typedef float v4f __attribute__((ext_vector_type(4)));
typedef float v2f __attribute__((ext_vector_type(2)));

#define PQ_ELEMS (CC * RIN * 64)     /* 1536 */
#define PQ_SIZE (PQ_ELEMS + 4)       /* +4 pad: last-row lanes read lane+kw<=67 */
#define WL_ELEMS (PP * 8)            /* 800: only this block's 8 features */
#define LDS_TOT (PQ_SIZE + WL_ELEMS) /* 2340 v4f = 37.4 KB */

// Round-7 = round-5 design with plain __launch_bounds__(512): two container
// failures on the (512,2) variant, and 1-arg launch_bounds ran fine in R4.
// Live-register budget now fits the default 128 cap naturally: qprev[5]=20 +
// qn=4 + 16 v2f accs=32 + 4 weight quads=16 + addr/temps ~20 => ~95 VGPR.
// Design: weight-amortization (1 wave-uniform weight-quad ds_read serves 2
// output rows), pixel rows shift through regs across kh; kh kept a real
// 5-iter loop (unroll 1) to stop cross-iteration load hoisting (R4's spill).
__global__ __launch_bounds__(512) void smorph_fused(
        const float* __restrict__ x, const float* __restrict__ k1,
        const float* __restrict__ k2, const float* __restrict__ bias,
        float* __restrict__ out) {
    __shared__ v4f lds[LDS_TOT];
    v4f* pq = lds;            // [c][rin][64] pixel quads {e^x, x e^x, e^-x, -x e^-x}
    v4f* wl = lds + PQ_SIZE;  // [p][side][f2l] weight quads {e^ka, e^kb, ka e^ka, kb e^kb}

    int b = blockIdx.x;       // 0..479 = (n, ho-pair, f-half)
    int n = b / (HPB * 2);
    int rem = b - n * (HPB * 2);
    int hp = rem >> 1;
    int fgh = rem & 1;        // feature half: features 8*fgh .. 8*fgh+7
    int ho0 = hp * RPB;
    int t = threadIdx.x;

    // Stage this f-half's weight exp-quads (800 elems; k1/k2 L2-resident).
    for (int i = t; i < WL_ELEMS; i += 512) {
        int p = i >> 3, r2 = i & 7, side = r2 >> 2, f2l = r2 & 3;
        int f2 = fgh * 4 + f2l; // global feature pair
        const float* kp = side ? k2 : k1;
        float ka = kp[p * FF + 2 * f2];
        float kb = kp[p * FF + 2 * f2 + 1];
        float ea = __expf(ka), eb = __expf(kb);
        wl[i] = (v4f){ea, eb, ka * ea, kb * eb};
    }
    // Stage pixel exp-quads: input rows ho0..ho0+5 (ho0<=58 -> row<=63), all c.
    for (int i = t; i < PQ_ELEMS; i += 512) {
        int w = i & 63;
        int cr = i >> 6; // c*RIN + r
        int c = cr / RIN, r = cr - c * RIN;
        float v = x[((n * CC + c) * HH + (ho0 + r)) * WW + w];
        float e1 = __expf(v), e2 = __expf(-v);
        pq[i] = (v4f){e1, v * e1, e2, -v * e2};
    }
    __syncthreads();

    int lane = t & 63;  // w position (60 used)
    int wid = t >> 6;   // 0..7
    int cw = wid & 3;   // channel owned by this wave
    int fgl = wid >> 2; // local feature group: local f-pairs 2fgl, 2fgl+1

    v2f d1[RPB][2], n1[RPB][2], d2[RPB][2], n2[RPB][2];
#pragma unroll
    for (int r = 0; r < RPB; ++r)
#pragma unroll
        for (int jp = 0; jp < 2; ++jp) {
            d1[r][jp] = 0.f; n1[r][jp] = 0.f;
            d2[r][jp] = 0.f; n2[r][jp] = 0.f;
        }

    const v4f* pbase = pq + (cw * RIN) * 64 + lane;
    const v4f* wbase = wl + cw * 8 + fgl * 2;

    // qprev holds input row kh's 5 shifted quads; row kh+1 loaded per-kw.
    v4f qprev[KK];
#pragma unroll
    for (int kw = 0; kw < KK; ++kw) qprev[kw] = pbase[kw];

#pragma unroll 1
    for (int kh = 0; kh < KK; ++kh) {
        const v4f* prow = pbase + (kh + 1) * 64; // input row kh+1
        const v4f* wrow = wbase + (kh * KK) * CC * 8;
#pragma unroll
        for (int kw = 0; kw < KK; ++kw) {
            v4f qn = prow[kw]; // row kh+1 quad (out row 1)
            // p = (kh*KK + kw)*CC + cw (reference patch order: kh,kw,c)
            const v4f* wp = wrow + kw * CC * 8;
            v4f w1a = wp[0], w1b = wp[1]; // side 1 (k1), local f-pairs
            v4f w2a = wp[4], w2b = wp[5]; // side 2 (k2)
            v4f q = qprev[kw];            // row kh quad (out row 0)
            d1[0][0] += q.xx * w1a.xy;
            n1[0][0] += q.yy * w1a.xy + q.xx * w1a.zw;
            d1[0][1] += q.xx * w1b.xy;
            n1[0][1] += q.yy * w1b.xy + q.xx * w1b.zw;
            d2[0][0] += q.zz * w2a.xy;
            n2[0][0] += q.ww * w2a.xy + q.zz * w2a.zw;
            d2[0][1] += q.zz * w2b.xy;
            n2[0][1] += q.ww * w2b.xy + q.zz * w2b.zw;
            d1[1][0] += qn.xx * w1a.xy;
            n1[1][0] += qn.yy * w1a.xy + qn.xx * w1a.zw;
            d1[1][1] += qn.xx * w1b.xy;
            n1[1][1] += qn.yy * w1b.xy + qn.xx * w1b.zw;
            d2[1][0] += qn.zz * w2a.xy;
            n2[1][0] += qn.ww * w2a.xy + qn.zz * w2a.zw;
            d2[1][1] += qn.zz * w2b.xy;
            n2[1][1] += qn.ww * w2b.xy + qn.zz * w2b.zw;
            qprev[kw] = qn; // shift: row kh+1 becomes row kh for next iter
        }
    }

    // 4-way c-reduction per row via LDS overlay (pq dead; 1536 v4f needed).
    // red[(cw-1)][fgl][acc 0..3][lane], acc packs {v[jp=0].xy, v[jp=1].xy}.
    v4f* red = lds;
    __syncthreads();
#pragma unroll
    for (int r = 0; r < RPB; ++r) {
        if (r) __syncthreads(); // row-0 reads done before row-1 overwrites
        if (cw) {
            v4f* rr = red + (((cw - 1) * 2 + fgl) * 4) * 64 + lane;
            rr[0 * 64] = (v4f){d1[r][0].x, d1[r][0].y, d1[r][1].x, d1[r][1].y};
            rr[1 * 64] = (v4f){n1[r][0].x, n1[r][0].y, n1[r][1].x, n1[r][1].y};
            rr[2 * 64] = (v4f){d2[r][0].x, d2[r][0].y, d2[r][1].x, d2[r][1].y};
            rr[3 * 64] = (v4f){n2[r][0].x, n2[r][0].y, n2[r][1].x, n2[r][1].y};
        }
        __syncthreads();
        if (!cw) {
#pragma unroll
            for (int rcw = 0; rcw < 3; ++rcw) {
                const v4f* rr = red + ((rcw * 2 + fgl) * 4) * 64 + lane;
                v4f t0 = rr[0 * 64], t1 = rr[1 * 64];
                v4f t2 = rr[2 * 64], t3 = rr[3 * 64];
                d1[r][0] += t0.xy; d1[r][1] += t0.zw;
                n1[r][0] += t1.xy; n1[r][1] += t1.zw;
                d2[r][0] += t2.xy; d2[r][1] += t2.zw;
                n2[r][0] += t3.xy; n2[r][1] += t3.zw;
            }
            if (lane < WO) {
                int ho = ho0 + r;
#pragma unroll
                for (int jp = 0; jp < 2; ++jp) {
                    v2f o = n1[r][jp] / d1[r][jp] + n2[r][jp] / d2[r][jp];
                    int f0 = fgh * 8 + fgl * 4 + 2 * jp;
                    out[((size_t)(n * FF + f0) * HO + ho) * WO + lane] =
                        o.x + bias[f0];
                    out[((size_t)(n * FF + f0 + 1) * HO + ho) * WO + lane] =
                        o.y + bias[f0 + 1];
                }
            }
        }
    }
}

extern "C" void kernel_launch(void* const* d_in, const int* in_sizes, int n_in,
                              void* d_out, int out_size, void* d_ws, size_t ws_size,
                              hipStream_t stream) {
    const float* x    = (const float*)d_in[0];
    const float* k1   = (const float*)d_in[1];
    const float* k2   = (const float*)d_in[2];
    const float* bias = (const float*)d_in[3];
    float* out = (float*)d_out;

    // 480 blocks = 8 n x 30 ho-pairs x 2 f-halves; 512 threads = 8 waves
    // (4 channels x 2 local f-groups), each wave: 2 rows x 4 features x 1 c.
    smorph_fused<<<NN * HPB * 2, 512, 0, stream>>>(x, k1, k2, bias, out);
}